// Round 2
// baseline (1022.023 us; speedup 1.0000x reference)
//
#include <hip/hip_runtime.h>
#include <hip/hip_bf16.h>

#define B_MESH 256
#define VPM    5850
#define NV     (B_MESH * VPM)   // 1497600
#define NE     (3 * NV)         // 4492800
#define NEB    ((NE + 255) / 256)   // 17550 edge blocks
#define KDIM   (VPM * 10)       // 58500
#define KP     58528            // KDIM padded to multiple of 32
#define KSPLIT 64
#define SLOPE  0.01f
#define NXCD   8                // MI355X XCD count (HW_REG_XCC_ID in 0..7)

// P3 packing (verts, 3ch): 3 x 19-bit biased limbs + 7-bit count.
#define LBIAS 4096
#define LMASK 0x7FFFFull
// x5 packing (5ch in one u64): 13/13/13/13/12 bits at shifts 0/13/26/39/52.
// limb = round(x*S)+bias, S=32 bias=125 (ch0-3), S=16 bias=63 (ch4). Safe deg<=32.
#define S5A   32.f
#define B5A   125
#define S5B   16.f
#define B5B   63
#define CLAMP5 3.9f

// init work carried in scat1's tail blocks
#define W2N    (64 * KP)                 // W2 -> bf16 elements
#define PADN   (B_MESH * (KP - KDIM))    // X10 pad elements

typedef short s8v  __attribute__((ext_vector_type(8)));
typedef float f4v  __attribute__((ext_vector_type(4)));

static __device__ __forceinline__ float b2f(__hip_bfloat16 h) { return __bfloat162float(h); }
static __device__ __forceinline__ __hip_bfloat16 f2b(float f) { return __float2bfloat16(f); }
static __device__ __forceinline__ float leaky(float x) { return x >= 0.f ? x : SLOPE * x; }

// Physical XCD of the CU this wave runs on. Block never migrates, all waves of a
// WG share one CU -> block-uniform. [measured: learn_hip m09, values 0..7]
static __device__ __forceinline__ unsigned xcc_id()
{
    unsigned x;
    asm("s_getreg_b32 %0, hwreg(HW_REG_XCC_ID)" : "=s"(x));
    return x & (NXCD - 1);
}

// NREP==8: workgroup-scope atomic -> RMW executes in the local (per-XCD) TCC,
// no sc1 write-through to the fabric. Each XCD only touches its own replica.
// NREP==1: plain device-scope atomic (baseline-proven fallback).
template<int NREP>
static __device__ __forceinline__ void acc_add(unsigned long long* p, unsigned long long v)
{
    if constexpr (NREP == NXCD)
        __hip_atomic_fetch_add(p, v, __ATOMIC_RELAXED, __HIP_MEMORY_SCOPE_WORKGROUP);
    else
        atomicAdd(p, v);
}

template<int NREP>
static __device__ __forceinline__ unsigned long long* rep_base(unsigned long long* R)
{
    if constexpr (NREP == NXCD) return R + (size_t)xcc_id() * NV;
    else return R;
}

static __device__ __forceinline__ unsigned long long pack3(float a, float b, float c,
                                                           float S, float clampv)
{
    int ia = __float2int_rn(fminf(fmaxf(a, -clampv), clampv) * S) + LBIAS;
    int ib = __float2int_rn(fminf(fmaxf(b, -clampv), clampv) * S) + LBIAS;
    int ic = __float2int_rn(fminf(fmaxf(c, -clampv), clampv) * S) + LBIAS;
    return (unsigned long long)(unsigned)ia
         | ((unsigned long long)(unsigned)ib << 19)
         | ((unsigned long long)(unsigned)ic << 38)
         | (1ull << 57);
}

static __device__ __forceinline__ void unpack3(unsigned long long p, float invS,
                                               float* o0, float* o1, float* o2, int* cnt)
{
    int c  = (int)(p >> 57);
    int l0 = (int)(p & LMASK);
    int l1 = (int)((p >> 19) & LMASK);
    int l2 = (int)((p >> 38) & LMASK);
    *o0 = (float)(l0 - c * LBIAS) * invS;
    *o1 = (float)(l1 - c * LBIAS) * invS;
    *o2 = (float)(l2 - c * LBIAS) * invS;
    *cnt = c;
}

static __device__ __forceinline__ unsigned long long pack5(const float* x)
{
    unsigned long long p = 0;
#pragma unroll
    for (int c = 0; c < 4; c++) {
        int l = __float2int_rn(fminf(fmaxf(x[c], -CLAMP5), CLAMP5) * S5A) + B5A;
        p |= (unsigned long long)(unsigned)l << (13 * c);
    }
    int l4 = __float2int_rn(fminf(fmaxf(x[4], -CLAMP5), CLAMP5) * S5B) + B5B;
    p |= (unsigned long long)(unsigned)l4 << 52;
    return p;
}

static __device__ __forceinline__ void unpack5(unsigned long long p, int deg, float* o)
{
    const float invA = 1.f / S5A, invB = 1.f / S5B;
#pragma unroll
    for (int c = 0; c < 4; c++) {
        int l = (int)((p >> (13 * c)) & 0x1FFF);
        o[c] = (float)(l - deg * B5A) * invA;
    }
    int l4 = (int)(p >> 52);
    o[4] = (float)(l4 - deg * B5B) * invB;
}

// ---------------- init: zero R (blocks [0,nzb)) + pack vq (blocks [nzb,...)) ----------------
// No hipMemsetAsync in the capture path; zeroing is a plain kernel.
__global__ void initK(const float* __restrict__ verts,
                      unsigned long long* __restrict__ R, long rWords, int nzb,
                      unsigned long long* __restrict__ vq)
{
    int b = blockIdx.x;
    if (b < nzb) {
        long base = ((long)b * 256 + threadIdx.x) * 4;
#pragma unroll
        for (int k = 0; k < 4; k++)
            if (base + k < rWords) R[base + k] = 0ull;
        return;
    }
    int t = (b - nzb) * 256 + threadIdx.x;
    if (t >= NV) return;
    float x0 = verts[3 * t + 0], x1 = verts[3 * t + 1], x2 = verts[3 * t + 2];
    vq[t] = pack3(x0, x1, x2, 512.f, 7.9f);
}

// ---------------- scatter 1 into replicas + free-rider init work ----------------
// Blocks [0,NEB): edge atomics. Blocks [NEB,...): W2 fp32->bf16 and X10 pad-zero.
template<int NREP>
__global__ void scat1K(const int2* __restrict__ edges,
                       const unsigned long long* __restrict__ vq,
                       unsigned long long* __restrict__ R,
                       const float* __restrict__ W2,
                       __hip_bfloat16* __restrict__ W2b,
                       __hip_bfloat16* __restrict__ X10)
{
    int b = blockIdx.x;
    if (b < NEB) {
        int e = b * 256 + threadIdx.x;
        if (e >= NE) return;
        int2 ij = edges[e];
        unsigned long long qi = vq[ij.x];
        unsigned long long qj = vq[ij.y];
        unsigned long long* Rx = rep_base<NREP>(R);
        acc_add<NREP>(&Rx[ij.x], qj);
        acc_add<NREP>(&Rx[ij.y], qi);
    } else {
        int idx = (b - NEB) * 256 + threadIdx.x;
        if (idx < W2N) {
            int n = idx / KP;
            int k = idx - n * KP;
            W2b[idx] = f2b(k < KDIM ? W2[(size_t)n * KDIM + k] : 0.f);
        } else if (idx < W2N + PADN) {
            int j = idx - W2N;
            int row = j / (KP - KDIM);
            int c   = j - row * (KP - KDIM);
            X10[(size_t)row * KP + KDIM + c] = f2b(0.f);
        }
    }
}

// ---------------- conv A: sum NREP replicas (additive packing), re-zero for pass B ----------------
template<int NREP>
__global__ void convAK(const float* __restrict__ verts,
                       unsigned long long* __restrict__ R,
                       const float* __restrict__ w0, const float* __restrict__ b0,
                       const float* __restrict__ w1, const float* __restrict__ b1,
                       unsigned long long* __restrict__ x5q,
                       unsigned char* __restrict__ deg8)
{
    int v = blockIdx.x * 256 + threadIdx.x;
    if (v >= NV) return;
    unsigned long long p = 0ull;
#pragma unroll
    for (int x = 0; x < NREP; x++) {
        size_t idx = (size_t)x * NV + v;
        p += R[idx];
        R[idx] = 0ull;          // reset for the 5-channel pass
    }
    float x0 = verts[3 * v + 0], x1 = verts[3 * v + 1], x2 = verts[3 * v + 2];
    float s0, s1, s2; int deg;
    unpack3(p, 1.f / 512.f, &s0, &s1, &s2, &deg);
    deg8[v] = (unsigned char)deg;
    float dg = (float)deg;
    float x5[5];
#pragma unroll
    for (int o = 0; o < 5; o++) {
        float a = b0[o] + dg * b1[o]
                + x0 * w0[o * 3 + 0] + x1 * w0[o * 3 + 1] + x2 * w0[o * 3 + 2]
                + s0 * w1[o * 3 + 0] + s1 * w1[o * 3 + 1] + s2 * w1[o * 3 + 2];
        x5[o] = leaky(a);
    }
    x5q[v] = pack5(x5);
}

// ---------------- scatter 5 into replicas ----------------
template<int NREP>
__global__ void scat5K(const int2* __restrict__ edges,
                       const unsigned long long* __restrict__ x5q,
                       unsigned long long* __restrict__ R)
{
    int e = blockIdx.x * 256 + threadIdx.x;
    if (e >= NE) return;
    int2 ij = edges[e];
    unsigned long long qi = x5q[ij.x];
    unsigned long long qj = x5q[ij.y];
    unsigned long long* Rx = rep_base<NREP>(R);
    acc_add<NREP>(&Rx[ij.x], qj);
    acc_add<NREP>(&Rx[ij.y], qi);
}

// ---------------- conv B (folded) + fc1 fused -> X10 bf16 (pitch KP) ----------------
template<int NREP>
__global__ void convBfc1(const unsigned long long* __restrict__ x5q,
                         const unsigned long long* __restrict__ R,
                         const unsigned char* __restrict__ deg8,
                         const float* __restrict__ w0, const float* __restrict__ b0,
                         const float* __restrict__ w1, const float* __restrict__ b1,
                         const float* __restrict__ fw, const float* __restrict__ fb,
                         __hip_bfloat16* __restrict__ X10)
{
    int v = blockIdx.x * 256 + threadIdx.x;
    if (v >= NV) return;
    int deg = (int)deg8[v];
    unsigned long long p = 0ull;
#pragma unroll
    for (int x = 0; x < NREP; x++) p += R[(size_t)x * NV + v];
    float xc[5], sc[5];
    unpack5(x5q[v], 1, xc);
    unpack5(p, deg, sc);
    float dg = (float)deg;
    float x20[20];
#pragma unroll
    for (int o = 0; o < 20; o++) {
        float a = b0[o] + dg * b1[o];
#pragma unroll
        for (int c = 0; c < 5; c++) a += xc[c] * w0[o * 5 + c] + sc[c] * w1[o * 5 + c];
        x20[o] = leaky(a);
    }
    int row = v / VPM;
    int vi  = v - row * VPM;
    __hip_bfloat16* dst = X10 + (size_t)row * KP + vi * 10;
#pragma unroll
    for (int o2 = 0; o2 < 10; o2++) {
        float a = fb[o2];
#pragma unroll
        for (int o = 0; o < 20; o++) a += x20[o] * fw[o2 * 20 + o];
        dst[o2] = f2b(leaky(a));
    }
}

// ---------------- MFMA GEMM: part[kc][256][64] = X10[256][KP](bf16) @ W2b[64][KP]^T ----------------
// grid (8 row-strips of 32, KSPLIT k-chunks) = 512 blocks (2/CU), 256 thr = 4 waves
__global__ void gemmMFMA(const __hip_bfloat16* __restrict__ X10,
                         const __hip_bfloat16* __restrict__ W2b,
                         float* __restrict__ part)
{
    int rt = blockIdx.x;               // 0..7
    int kc = blockIdx.y;               // 0..63
    int w    = threadIdx.x >> 6;
    int lane = threadIdx.x & 63;
    int quad = lane >> 4;
    int ml   = lane & 15;
    // 1829 K-steps of 32: 37 chunks of 29 + 27 chunks of 28
    int s0  = kc * 28 + min(kc, 37);
    int len = 28 + (kc < 37 ? 1 : 0);

    const s8v* a0p = (const s8v*)(X10 + (size_t)(rt * 32 + ml) * KP + s0 * 32 + quad * 8);
    const s8v* a1p = (const s8v*)((const __hip_bfloat16*)a0p + (size_t)16 * KP);
    const s8v* bp  = (const s8v*)(W2b + (size_t)(w * 16 + ml) * KP + s0 * 32 + quad * 8);

    f4v c0 = {0.f, 0.f, 0.f, 0.f};
    f4v c1 = {0.f, 0.f, 0.f, 0.f};
    for (int s = 0; s < len; s++) {
        s8v a0 = a0p[s * 4];           // s8v = 16B, K-step 32 bf16 = 4 vectors
        s8v a1 = a1p[s * 4];
        s8v b  = bp[s * 4];
        c0 = __builtin_amdgcn_mfma_f32_16x16x32_bf16(a0, b, c0, 0, 0, 0);
        c1 = __builtin_amdgcn_mfma_f32_16x16x32_bf16(a1, b, c1, 0, 0, 0);
    }
    // C/D: col n = ml, row m = quad*4 + reg
    float* pbase = part + ((size_t)kc * B_MESH + rt * 32) * 64;
#pragma unroll
    for (int r = 0; r < 4; r++) {
        pbase[(quad * 4 + r) * 64 + w * 16 + ml]        = c0[r];
        pbase[(16 + quad * 4 + r) * 64 + w * 16 + ml]   = c1[r];
    }
}

// ---------------- reduce partials + bias + softmax ----------------
__global__ void reduceSoftmax(const float* __restrict__ part,
                              const float* __restrict__ fb2,
                              float* __restrict__ out)
{
    int b = blockIdx.x;
    int n = threadIdx.x;   // 64
    float acc = fb2[n];
#pragma unroll 8
    for (int p = 0; p < KSPLIT; p++) acc += part[((size_t)p * B_MESH + b) * 64 + n];
    float m = acc;
#pragma unroll
    for (int off = 32; off; off >>= 1) m = fmaxf(m, __shfl_xor(m, off, 64));
    float e = __expf(acc - m);
    float s = e;
#pragma unroll
    for (int off = 32; off; off >>= 1) s += __shfl_xor(s, off, 64);
    out[b * 64 + n] = e / s;
}

extern "C" void kernel_launch(void* const* d_in, const int* in_sizes, int n_in,
                              void* d_out, int out_size, void* d_ws, size_t ws_size,
                              hipStream_t stream)
{
    const float* verts = (const float*)d_in[0];
    const int*   edges = (const int*)d_in[1];
    const float* w0a   = (const float*)d_in[2];
    const float* b0a   = (const float*)d_in[3];
    const float* w1a   = (const float*)d_in[4];
    const float* b1a   = (const float*)d_in[5];
    const float* w0b   = (const float*)d_in[6];
    const float* b0b   = (const float*)d_in[7];
    const float* w1b   = (const float*)d_in[8];
    const float* b1b   = (const float*)d_in[9];
    const float* fc1w  = (const float*)d_in[10];
    const float* fc1b  = (const float*)d_in[11];
    const float* fc2w  = (const float*)d_in[12];
    const float* fc2b  = (const float*)d_in[13];

    // ---- workspace layout, runtime-dispatched on ws_size ----
    const size_t SZ_R1  = (size_t)NV * 8;                  // 12 MB
    const size_t SZ_R8  = (size_t)NXCD * NV * 8;           // 95.8 MB
    const size_t SZ_VQX = (size_t)NV * 8;                  // 12 MB (vq then x5q)
    const size_t SZ_X10 = (size_t)B_MESH * KP * 2;         // 30 MB
    const size_t SZ_W2B = (size_t)64 * KP * 2;             // 7.5 MB
    const size_t SZ_DEG = (size_t)NV;                      // 1.5 MB
    // part (4 MB) always aliases R: R is dead after convBfc1, before gemm writes part.
    const size_t needRep = SZ_R8 + SZ_VQX + SZ_X10 + SZ_W2B + SZ_DEG;   // ~147 MB

    bool rep = ws_size >= needRep;
    size_t szR = rep ? SZ_R8 : SZ_R1;

    char* ws = (char*)d_ws;
    unsigned long long* R    = (unsigned long long*)(ws);
    unsigned long long* vqx  = (unsigned long long*)(ws + szR);           // vq / x5q shared
    __hip_bfloat16*     X10  = (__hip_bfloat16*)(ws + szR + SZ_VQX);
    __hip_bfloat16*     W2b  = (__hip_bfloat16*)(ws + szR + SZ_VQX + SZ_X10);
    unsigned char*      deg8 = (unsigned char*)(ws + szR + SZ_VQX + SZ_X10 + SZ_W2B);
    float*              part = (float*)R;                                 // alias (see above)

    long rWords = (long)(szR / 8);
    int  nzb    = (int)((rWords / 4 + 255) / 256);     // zeroing blocks (4 u64/thread)
    int  nvb    = (NV + 255) / 256;                    // 5850
    int  ntail  = (W2N + PADN + 255) / 256;            // ~14661
    int  ns1    = NEB + ntail;                         // scat1 grid incl. free-riders

    initK<<<nzb + nvb, 256, 0, stream>>>(verts, R, rWords, nzb, vqx);
    if (rep) {
        scat1K<NXCD><<<ns1, 256, 0, stream>>>((const int2*)edges, vqx, R, fc2w, W2b, X10);
        convAK<NXCD><<<nvb, 256, 0, stream>>>(verts, R, w0a, b0a, w1a, b1a, vqx, deg8);
        scat5K<NXCD><<<NEB, 256, 0, stream>>>((const int2*)edges, vqx, R);
        convBfc1<NXCD><<<nvb, 256, 0, stream>>>(vqx, R, deg8, w0b, b0b, w1b, b1b, fc1w, fc1b, X10);
    } else {
        scat1K<1><<<ns1, 256, 0, stream>>>((const int2*)edges, vqx, R, fc2w, W2b, X10);
        convAK<1><<<nvb, 256, 0, stream>>>(verts, R, w0a, b0a, w1a, b1a, vqx, deg8);
        scat5K<1><<<NEB, 256, 0, stream>>>((const int2*)edges, vqx, R);
        convBfc1<1><<<nvb, 256, 0, stream>>>(vqx, R, deg8, w0b, b0b, w1b, b1b, fc1w, fc1b, X10);
    }
    gemmMFMA<<<dim3(8, KSPLIT), 256, 0, stream>>>(X10, W2b, part);
    reduceSoftmax<<<B_MESH, 64, 0, stream>>>(part, fc2b, (float*)d_out);
}